// Round 4
// baseline (703.659 us; speedup 1.0000x reference)
//
#include <hip/hip_runtime.h>
#include <hip/hip_bf16.h>

using bf16 = __hip_bfloat16;
using floatx4 = __attribute__((ext_vector_type(4))) float;
using bf16x8  = __attribute__((ext_vector_type(8))) __bf16;
using bf16x2  = __attribute__((ext_vector_type(2))) __bf16;

#define MDIM 8192   // B*T
#define NDIM 2048   // C
#define KDIM 2048   // C
#define TSEQ 2048   // T
#define BB   4      // batch
#define CDIM 2048   // C
#define NCHUNK 64
#define TCHUNK 32   // TSEQ/NCHUNK

typedef __attribute__((address_space(1))) void gvoid_t;
typedef __attribute__((address_space(3))) void lvoid_t;

__device__ __forceinline__ void load_lds16(const void* g, void* l) {
  __builtin_amdgcn_global_load_lds((gvoid_t*)(void*)g, (lvoid_t*)l, 16, 0, 0);
}

// ---------------- fp32 -> bf16 converts ---------------------------------------
__global__ __launch_bounds__(256) void cvt_x(const float* __restrict__ s,
                                             __bf16* __restrict__ d) {
  const int i = (blockIdx.x * 256 + threadIdx.x) * 8;
  float4 a = *(const float4*)(s + i);
  float4 b = *(const float4*)(s + i + 4);
  bf16x8 o;
  o[0] = (__bf16)a.x; o[1] = (__bf16)a.y; o[2] = (__bf16)a.z; o[3] = (__bf16)a.w;
  o[4] = (__bf16)b.x; o[5] = (__bf16)b.y; o[6] = (__bf16)b.z; o[7] = (__bf16)b.w;
  *(bf16x8*)(d + i) = o;
}

__global__ __launch_bounds__(256) void cvt_w(const float* __restrict__ s0,
                                             const float* __restrict__ s1,
                                             const float* __restrict__ s2,
                                             const float* __restrict__ s3,
                                             __bf16* __restrict__ d0,
                                             __bf16* __restrict__ d1,
                                             __bf16* __restrict__ d2,
                                             __bf16* __restrict__ d3) {
  const float* s = (blockIdx.y == 0) ? s0 : (blockIdx.y == 1) ? s1
                 : (blockIdx.y == 2) ? s2 : s3;
  __bf16*      d = (blockIdx.y == 0) ? d0 : (blockIdx.y == 1) ? d1
                 : (blockIdx.y == 2) ? d2 : d3;
  const int i = (blockIdx.x * 256 + threadIdx.x) * 8;
  float4 a = *(const float4*)(s + i);
  float4 b = *(const float4*)(s + i + 4);
  bf16x8 o;
  o[0] = (__bf16)a.x; o[1] = (__bf16)a.y; o[2] = (__bf16)a.z; o[3] = (__bf16)a.w;
  o[4] = (__bf16)b.x; o[5] = (__bf16)b.y; o[6] = (__bf16)b.z; o[7] = (__bf16)b.w;
  *(bf16x8*)(d + i) = o;
}

// ---------------- GEMM: C[m,n] = sum_k A[m,k] * B[n,k], bf16 in, fp32 acc -----
// 128x128 tile, BK=32, 256 threads = 4 waves in 2x2, each wave 4x4 MFMA 16x16x32.
// LDS layout is chunk-permuted: 16B chunk (row r, col-half h) lives at chunk
// index (r>>4)*64 + h*16 + (r&15). Frag reads are then base + lane*16B
// (lane-consecutive => minimal bank conflicts); staging source is permuted to
// match since global_load_lds dest is fixed at lane*16B.
template <typename CT>
__device__ __forceinline__ void gemm_body(const __bf16* __restrict__ A,
                                          const __bf16* __restrict__ B,
                                          CT* __restrict__ C) {
  __shared__ __bf16 sA[128 * 32];
  __shared__ __bf16 sB[128 * 32];
  const int tid  = threadIdx.x;
  const int lane = tid & 63;
  const int wave = tid >> 6;
  const int wm = (wave >> 1) * 64;
  const int wn = (wave & 1) * 64;
  const int bm = blockIdx.x, bn = blockIdx.y;

  floatx4 acc[4][4] = {};

  // staging source for LDS chunk `tid`: decode pos -> (row, col-half)
  const int srow = ((tid >> 6) << 4) + (tid & 15);   // 0..63
  const int scol = ((tid >> 4) & 3) * 8;             // 0,8,16,24
  const __bf16* Ag = A + (size_t)(bm * 128 + srow) * KDIM + scol;
  const __bf16* Bg = B + (size_t)(bn * 128 + srow) * KDIM + scol;
  __bf16* sAp = sA + tid * 8;   // dest: chunk tid (16B)
  __bf16* sBp = sB + tid * 8;

  const int rbA = (wm >> 4);    // 0 or 4: row-block base for frag reads
  const int rbB = (wn >> 4);

  for (int kt = 0; kt < KDIM; kt += 32) {
    load_lds16(Ag,                      sAp);
    load_lds16(Ag + (size_t)64 * KDIM,  sAp + 2048);  // chunks 256..511 = rows 64..127
    load_lds16(Bg,                      sBp);
    load_lds16(Bg + (size_t)64 * KDIM,  sBp + 2048);
    Ag += 32; Bg += 32;
    __syncthreads();

    bf16x8 af[4], bfr[4];
#pragma unroll
    for (int i = 0; i < 4; ++i)
      af[i] = *(const bf16x8*)(sA + (rbA + i) * 512 + lane * 8);
#pragma unroll
    for (int j = 0; j < 4; ++j)
      bfr[j] = *(const bf16x8*)(sB + (rbB + j) * 512 + lane * 8);
#pragma unroll
    for (int i = 0; i < 4; ++i)
#pragma unroll
      for (int j = 0; j < 4; ++j)
        acc[i][j] = __builtin_amdgcn_mfma_f32_16x16x32_bf16(af[i], bfr[j], acc[i][j], 0, 0, 0);
    __syncthreads();
  }

  // C/D layout: col = lane&15, row = (lane>>4)*4 + reg
  const int crow = (lane >> 4) * 4;
  const int ccol = lane & 15;
#pragma unroll
  for (int i = 0; i < 4; ++i)
#pragma unroll
    for (int j = 0; j < 4; ++j) {
      const size_t r0 = (size_t)(bm * 128 + wm + i * 16 + crow);
      const int    c0 = bn * 128 + wn + j * 16 + ccol;
#pragma unroll
      for (int rg = 0; rg < 4; ++rg)
        C[(r0 + rg) * NDIM + c0] = (CT)(acc[i][j][rg]);
    }
}

__global__ __launch_bounds__(256) void gemm_qkv(const __bf16* __restrict__ x,
                                                const __bf16* __restrict__ Wk,
                                                const __bf16* __restrict__ Wv,
                                                const __bf16* __restrict__ Wr,
                                                __bf16* __restrict__ kb,
                                                __bf16* __restrict__ vb,
                                                __bf16* __restrict__ rb) {
  const __bf16* Bsel = (blockIdx.z == 0) ? Wk : (blockIdx.z == 1) ? Wv : Wr;
  __bf16*       Csel = (blockIdx.z == 0) ? kb : (blockIdx.z == 1) ? vb : rb;
  gemm_body<__bf16>(x, Bsel, Csel);
}

__global__ __launch_bounds__(256) void gemm_o(const __bf16* __restrict__ A,
                                              const __bf16* __restrict__ B,
                                              float* __restrict__ C) {
  gemm_body<float>(A, B, C);
}

// ---------------- WKV blocked scan: 2 channels/thread --------------------------
__global__ __launch_bounds__(256) void wkv_summary(
    const __bf16* __restrict__ kb, const __bf16* __restrict__ vb,
    const float* __restrict__ td, const float* __restrict__ tf,
    float* __restrict__ nsum, float* __restrict__ dsum) {
  const int c0 = (blockIdx.x * 256 + threadIdx.x) * 2;
  const int chunk = blockIdx.y;
  const int b = blockIdx.z;
  const float dc0 = __expf(-__expf(td[c0]));
  const float dc1 = __expf(-__expf(td[c0 + 1]));
  const float fi0 = __expf(tf[c0]);
  const float fi1 = __expf(tf[c0 + 1]);
  size_t base = ((size_t)b * TSEQ + (size_t)chunk * TCHUNK) * CDIM + c0;
  float n0 = 0.f, d0 = 0.f, n1 = 0.f, d1 = 0.f;
#pragma unroll 4
  for (int t = 0; t < TCHUNK; ++t) {
    bf16x2 k2 = *(const bf16x2*)(kb + base + (size_t)t * CDIM);
    bf16x2 v2 = *(const bf16x2*)(vb + base + (size_t)t * CDIM);
    float k0f = fminf(fmaxf((float)k2[0], -10.f), 10.f);
    float k1f = fminf(fmaxf((float)k2[1], -10.f), 10.f);
    float w0 = __expf(k0f), w1 = __expf(k1f);
    if (chunk == 0 && t == 0) { w0 *= fi0; w1 *= fi1; }
    n0 = dc0 * n0 + w0 * (float)v2[0];
    d0 = dc0 * d0 + w0;
    n1 = dc1 * n1 + w1 * (float)v2[1];
    d1 = dc1 * d1 + w1;
  }
  const size_t si = (size_t)(chunk * BB + b) * CDIM + c0;
  *(float2*)(nsum + si) = make_float2(n0, n1);
  *(float2*)(dsum + si) = make_float2(d0, d1);
}

__global__ __launch_bounds__(256) void wkv_apply(
    const __bf16* __restrict__ kb, const __bf16* __restrict__ vb,
    __bf16* __restrict__ rb,
    const float* __restrict__ td, const float* __restrict__ tf,
    const float* __restrict__ nsum, const float* __restrict__ dsum) {
  const int c0 = (blockIdx.x * 256 + threadIdx.x) * 2;
  const int chunk = blockIdx.y;
  const int b = blockIdx.z;
  const float ed0 = __expf(td[c0]);
  const float ed1 = __expf(td[c0 + 1]);
  const float dc0 = __expf(-ed0);
  const float dc1 = __expf(-ed1);
  const float dT0 = __expf(-ed0 * (float)TCHUNK);  // decay^TCHUNK
  const float dT1 = __expf(-ed1 * (float)TCHUNK);
  const float fi0 = __expf(tf[c0]);
  const float fi1 = __expf(tf[c0 + 1]);

  float n0 = 0.f, d0 = 0.f, n1 = 0.f, d1 = 0.f;
  for (int j = 0; j < chunk; ++j) {
    const size_t si = (size_t)(j * BB + b) * CDIM + c0;
    float2 ns = *(const float2*)(nsum + si);
    float2 ds = *(const float2*)(dsum + si);
    n0 = dT0 * n0 + ns.x;  d0 = dT0 * d0 + ds.x;
    n1 = dT1 * n1 + ns.y;  d1 = dT1 * d1 + ds.y;
  }
  size_t base = ((size_t)b * TSEQ + (size_t)chunk * TCHUNK) * CDIM + c0;
#pragma unroll 2
  for (int t = 0; t < TCHUNK; ++t) {
    const size_t idx = base + (size_t)t * CDIM;
    bf16x2 k2 = *(const bf16x2*)(kb + idx);
    bf16x2 v2 = *(const bf16x2*)(vb + idx);
    bf16x2 r2 = *(const bf16x2*)(rb + idx);
    float k0f = fminf(fmaxf((float)k2[0], -10.f), 10.f);
    float k1f = fminf(fmaxf((float)k2[1], -10.f), 10.f);
    float w0 = __expf(k0f), w1 = __expf(k1f);
    if (chunk == 0 && t == 0) { w0 *= fi0; w1 *= fi1; }
    n0 = dc0 * n0 + w0 * (float)v2[0];
    d0 = dc0 * d0 + w0;
    n1 = dc1 * n1 + w1 * (float)v2[1];
    d1 = dc1 * d1 + w1;
    const float wkv0 = n0 * __builtin_amdgcn_rcpf(d0 + 1e-6f);
    const float wkv1 = n1 * __builtin_amdgcn_rcpf(d1 + 1e-6f);
    const float sr0 = __builtin_amdgcn_rcpf(1.f + __expf(-(float)r2[0]));
    const float sr1 = __builtin_amdgcn_rcpf(1.f + __expf(-(float)r2[1]));
    bf16x2 o;
    o[0] = (__bf16)(sr0 * wkv0);
    o[1] = (__bf16)(sr1 * wkv1);
    *(bf16x2*)(rb + idx) = o;
  }
}

// ---------------- launch -------------------------------------------------------
extern "C" void kernel_launch(void* const* d_in, const int* in_sizes, int n_in,
                              void* d_out, int out_size, void* d_ws, size_t ws_size,
                              hipStream_t stream) {
  const float* x  = (const float*)d_in[0];
  const float* Wk = (const float*)d_in[1];
  const float* Wv = (const float*)d_in[2];
  const float* Wr = (const float*)d_in[3];
  const float* Wo = (const float*)d_in[4];
  const float* td = (const float*)d_in[5];
  const float* tf = (const float*)d_in[6];
  float* out = (float*)d_out;

  char* ws = (char*)d_ws;
  const size_t matX = (size_t)MDIM * KDIM * sizeof(__bf16);  // 33.5 MB
  const size_t matW = (size_t)NDIM * KDIM * sizeof(__bf16);  // 8.4 MB
  __bf16* xb  = (__bf16*)(ws);
  __bf16* wkb = (__bf16*)(ws + matX);
  __bf16* wvb = (__bf16*)(ws + matX + matW);
  __bf16* wrb = (__bf16*)(ws + matX + 2 * matW);
  __bf16* wob = (__bf16*)(ws + matX + 3 * matW);
  __bf16* kb  = (__bf16*)(ws + matX + 4 * matW);
  __bf16* vb  = (__bf16*)(ws + 2 * matX + 4 * matW);
  __bf16* rb  = (__bf16*)(ws + 3 * matX + 4 * matW);
  float* nsum = (float*)(ws + 4 * matX + 4 * matW);
  float* dsum = nsum + (size_t)NCHUNK * BB * CDIM;
  // ws use: 4*33.5MB + 4*8.4MB + 4MB ~= 172 MB

  dim3 blk(256);
  cvt_x<<<dim3(MDIM * KDIM / (8 * 256)), blk, 0, stream>>>(x, xb);
  cvt_w<<<dim3(NDIM * KDIM / (8 * 256), 4), blk, 0, stream>>>(
      Wk, Wv, Wr, Wo, wkb, wvb, wrb, wob);

  dim3 gq(MDIM / 128, NDIM / 128, 3);
  gemm_qkv<<<gq, blk, 0, stream>>>(xb, wkb, wvb, wrb, kb, vb, rb);
  dim3 gw(CDIM / 512, NCHUNK, BB);
  wkv_summary<<<gw, blk, 0, stream>>>(kb, vb, td, tf, nsum, dsum);
  wkv_apply<<<gw, blk, 0, stream>>>(kb, vb, rb, td, tf, nsum, dsum);
  dim3 go(MDIM / 128, NDIM / 128, 1);
  gemm_o<<<go, blk, 0, stream>>>(rb, wob, out);
}

// Round 5
// 528.701 us; speedup vs baseline: 1.3309x; 1.3309x over previous
//
#include <hip/hip_runtime.h>
#include <hip/hip_bf16.h>

using bf16 = __hip_bfloat16;
using floatx4 = __attribute__((ext_vector_type(4))) float;
using bf16x8  = __attribute__((ext_vector_type(8))) __bf16;
using bf16x2  = __attribute__((ext_vector_type(2))) __bf16;

#define MDIM 8192   // B*T
#define NDIM 2048   // C
#define KDIM 2048   // C
#define TSEQ 2048   // T
#define BB   4      // batch
#define CDIM 2048   // C
#define NCHUNK 64
#define TCHUNK 32   // TSEQ/NCHUNK

typedef __attribute__((address_space(1))) void gvoid_t;
typedef __attribute__((address_space(3))) void lvoid_t;

__device__ __forceinline__ void load_lds16(const void* g, void* l) {
  __builtin_amdgcn_global_load_lds((gvoid_t*)(void*)g, (lvoid_t*)l, 16, 0, 0);
}

// ---------------- fp32 -> bf16 converts ---------------------------------------
__global__ __launch_bounds__(256) void cvt_x(const float* __restrict__ s,
                                             __bf16* __restrict__ d) {
  const int i = (blockIdx.x * 256 + threadIdx.x) * 8;
  float4 a = *(const float4*)(s + i);
  float4 b = *(const float4*)(s + i + 4);
  bf16x8 o;
  o[0] = (__bf16)a.x; o[1] = (__bf16)a.y; o[2] = (__bf16)a.z; o[3] = (__bf16)a.w;
  o[4] = (__bf16)b.x; o[5] = (__bf16)b.y; o[6] = (__bf16)b.z; o[7] = (__bf16)b.w;
  *(bf16x8*)(d + i) = o;
}

__global__ __launch_bounds__(256) void cvt_w(const float* __restrict__ s0,
                                             const float* __restrict__ s1,
                                             const float* __restrict__ s2,
                                             const float* __restrict__ s3,
                                             __bf16* __restrict__ d0,
                                             __bf16* __restrict__ d1,
                                             __bf16* __restrict__ d2,
                                             __bf16* __restrict__ d3) {
  const float* s = (blockIdx.y == 0) ? s0 : (blockIdx.y == 1) ? s1
                 : (blockIdx.y == 2) ? s2 : s3;
  __bf16*      d = (blockIdx.y == 0) ? d0 : (blockIdx.y == 1) ? d1
                 : (blockIdx.y == 2) ? d2 : d3;
  const int i = (blockIdx.x * 256 + threadIdx.x) * 8;
  float4 a = *(const float4*)(s + i);
  float4 b = *(const float4*)(s + i + 4);
  bf16x8 o;
  o[0] = (__bf16)a.x; o[1] = (__bf16)a.y; o[2] = (__bf16)a.z; o[3] = (__bf16)a.w;
  o[4] = (__bf16)b.x; o[5] = (__bf16)b.y; o[6] = (__bf16)b.z; o[7] = (__bf16)b.w;
  *(bf16x8*)(d + i) = o;
}

// ---------------- GEMM: C[m,n] = sum_k A[m,k] * B[n,k], bf16 in, fp32 acc -----
// 128x128 tile, BK=32, 256 threads = 4 waves in 2x2, each wave 4x4 MFMA 16x16x32.
// LDS XOR-swizzle: 16B chunk (row r, col-half h) stored at chunk index
//   r*4 + (h ^ ((r>>1)&3)).
// Staging: thread tid -> dest chunk tid, source row tid>>2, half (tid&3)^((tid>>3)&3);
//   each 4-lane group covers one contiguous 64B line (permuted within) => coalesced.
// Frag reads: consecutive 8 lanes tile all 8 bank-groups => conflict-free.
template <typename CT>
__device__ __forceinline__ void gemm_body(const __bf16* __restrict__ A,
                                          const __bf16* __restrict__ B,
                                          CT* __restrict__ C) {
  __shared__ __bf16 sA[128 * 32];
  __shared__ __bf16 sB[128 * 32];
  const int tid  = threadIdx.x;
  const int lane = tid & 63;
  const int wave = tid >> 6;
  const int wm = (wave >> 1) * 64;
  const int wn = (wave & 1) * 64;
  const int bm = blockIdx.x, bn = blockIdx.y;

  floatx4 acc[4][4] = {};

  // staging source (swizzled within 64B line)
  const int srow  = tid >> 2;                       // 0..63
  const int shalf = (tid & 3) ^ ((tid >> 3) & 3);   // within-line permute
  const __bf16* Ag = A + (size_t)(bm * 128 + srow) * KDIM + shalf * 8;
  const __bf16* Bg = B + (size_t)(bn * 128 + srow) * KDIM + shalf * 8;
  __bf16* sAp = sA + tid * 8;   // dest chunk tid
  __bf16* sBp = sB + tid * 8;

  // frag-read chunk indices (K-loop-invariant)
  const int fr  = lane & 15;
  const int fk4 = lane >> 4;
  int chA[4], chB[4];
#pragma unroll
  for (int i = 0; i < 4; ++i) {
    const int ra = wm + i * 16 + fr;
    const int rb = wn + i * 16 + fr;
    chA[i] = (ra << 2) | (fk4 ^ ((ra >> 1) & 3));
    chB[i] = (rb << 2) | (fk4 ^ ((rb >> 1) & 3));
  }

  for (int kt = 0; kt < KDIM; kt += 32) {
    load_lds16(Ag,                      sAp);
    load_lds16(Ag + (size_t)64 * KDIM,  sAp + 2048);  // chunks 256..511 = rows 64..127
    load_lds16(Bg,                      sBp);
    load_lds16(Bg + (size_t)64 * KDIM,  sBp + 2048);
    Ag += 32; Bg += 32;
    __syncthreads();

    bf16x8 af[4], bfr[4];
#pragma unroll
    for (int i = 0; i < 4; ++i)
      af[i] = *(const bf16x8*)(sA + chA[i] * 8);
#pragma unroll
    for (int j = 0; j < 4; ++j)
      bfr[j] = *(const bf16x8*)(sB + chB[j] * 8);
#pragma unroll
    for (int i = 0; i < 4; ++i)
#pragma unroll
      for (int j = 0; j < 4; ++j)
        acc[i][j] = __builtin_amdgcn_mfma_f32_16x16x32_bf16(af[i], bfr[j], acc[i][j], 0, 0, 0);
    __syncthreads();
  }

  // C/D layout: col = lane&15, row = (lane>>4)*4 + reg
  const int crow = (lane >> 4) * 4;
  const int ccol = lane & 15;
#pragma unroll
  for (int i = 0; i < 4; ++i)
#pragma unroll
    for (int j = 0; j < 4; ++j) {
      const size_t r0 = (size_t)(bm * 128 + wm + i * 16 + crow);
      const int    c0 = bn * 128 + wn + j * 16 + ccol;
#pragma unroll
      for (int rg = 0; rg < 4; ++rg)
        C[(r0 + rg) * NDIM + c0] = (CT)(acc[i][j][rg]);
    }
}

__global__ __launch_bounds__(256) void gemm_qkv(const __bf16* __restrict__ x,
                                                const __bf16* __restrict__ Wk,
                                                const __bf16* __restrict__ Wv,
                                                const __bf16* __restrict__ Wr,
                                                __bf16* __restrict__ kb,
                                                __bf16* __restrict__ vb,
                                                __bf16* __restrict__ rb) {
  const __bf16* Bsel = (blockIdx.z == 0) ? Wk : (blockIdx.z == 1) ? Wv : Wr;
  __bf16*       Csel = (blockIdx.z == 0) ? kb : (blockIdx.z == 1) ? vb : rb;
  gemm_body<__bf16>(x, Bsel, Csel);
}

__global__ __launch_bounds__(256) void gemm_o(const __bf16* __restrict__ A,
                                              const __bf16* __restrict__ B,
                                              float* __restrict__ C) {
  gemm_body<float>(A, B, C);
}

// ---------------- WKV blocked scan: 2 channels/thread --------------------------
__global__ __launch_bounds__(256) void wkv_summary(
    const __bf16* __restrict__ kb, const __bf16* __restrict__ vb,
    const float* __restrict__ td, const float* __restrict__ tf,
    float* __restrict__ nsum, float* __restrict__ dsum) {
  const int c0 = (blockIdx.x * 256 + threadIdx.x) * 2;
  const int chunk = blockIdx.y;
  const int b = blockIdx.z;
  const float dc0 = __expf(-__expf(td[c0]));
  const float dc1 = __expf(-__expf(td[c0 + 1]));
  const float fi0 = __expf(tf[c0]);
  const float fi1 = __expf(tf[c0 + 1]);
  size_t base = ((size_t)b * TSEQ + (size_t)chunk * TCHUNK) * CDIM + c0;
  float n0 = 0.f, d0 = 0.f, n1 = 0.f, d1 = 0.f;
#pragma unroll 4
  for (int t = 0; t < TCHUNK; ++t) {
    bf16x2 k2 = *(const bf16x2*)(kb + base + (size_t)t * CDIM);
    bf16x2 v2 = *(const bf16x2*)(vb + base + (size_t)t * CDIM);
    float k0f = fminf(fmaxf((float)k2[0], -10.f), 10.f);
    float k1f = fminf(fmaxf((float)k2[1], -10.f), 10.f);
    float w0 = __expf(k0f), w1 = __expf(k1f);
    if (chunk == 0 && t == 0) { w0 *= fi0; w1 *= fi1; }
    n0 = dc0 * n0 + w0 * (float)v2[0];
    d0 = dc0 * d0 + w0;
    n1 = dc1 * n1 + w1 * (float)v2[1];
    d1 = dc1 * d1 + w1;
  }
  const size_t si = (size_t)(chunk * BB + b) * CDIM + c0;
  *(float2*)(nsum + si) = make_float2(n0, n1);
  *(float2*)(dsum + si) = make_float2(d0, d1);
}

__global__ __launch_bounds__(256) void wkv_apply(
    const __bf16* __restrict__ kb, const __bf16* __restrict__ vb,
    __bf16* __restrict__ rb,
    const float* __restrict__ td, const float* __restrict__ tf,
    const float* __restrict__ nsum, const float* __restrict__ dsum) {
  const int c0 = (blockIdx.x * 256 + threadIdx.x) * 2;
  const int chunk = blockIdx.y;
  const int b = blockIdx.z;
  const float ed0 = __expf(td[c0]);
  const float ed1 = __expf(td[c0 + 1]);
  const float dc0 = __expf(-ed0);
  const float dc1 = __expf(-ed1);
  const float dT0 = __expf(-ed0 * (float)TCHUNK);  // decay^TCHUNK
  const float dT1 = __expf(-ed1 * (float)TCHUNK);
  const float fi0 = __expf(tf[c0]);
  const float fi1 = __expf(tf[c0 + 1]);

  float n0 = 0.f, d0 = 0.f, n1 = 0.f, d1 = 0.f;
  for (int j = 0; j < chunk; ++j) {
    const size_t si = (size_t)(j * BB + b) * CDIM + c0;
    float2 ns = *(const float2*)(nsum + si);
    float2 ds = *(const float2*)(dsum + si);
    n0 = dT0 * n0 + ns.x;  d0 = dT0 * d0 + ds.x;
    n1 = dT1 * n1 + ns.y;  d1 = dT1 * d1 + ds.y;
  }
  size_t base = ((size_t)b * TSEQ + (size_t)chunk * TCHUNK) * CDIM + c0;
#pragma unroll 2
  for (int t = 0; t < TCHUNK; ++t) {
    const size_t idx = base + (size_t)t * CDIM;
    bf16x2 k2 = *(const bf16x2*)(kb + idx);
    bf16x2 v2 = *(const bf16x2*)(vb + idx);
    bf16x2 r2 = *(const bf16x2*)(rb + idx);
    float k0f = fminf(fmaxf((float)k2[0], -10.f), 10.f);
    float k1f = fminf(fmaxf((float)k2[1], -10.f), 10.f);
    float w0 = __expf(k0f), w1 = __expf(k1f);
    if (chunk == 0 && t == 0) { w0 *= fi0; w1 *= fi1; }
    n0 = dc0 * n0 + w0 * (float)v2[0];
    d0 = dc0 * d0 + w0;
    n1 = dc1 * n1 + w1 * (float)v2[1];
    d1 = dc1 * d1 + w1;
    const float wkv0 = n0 * __builtin_amdgcn_rcpf(d0 + 1e-6f);
    const float wkv1 = n1 * __builtin_amdgcn_rcpf(d1 + 1e-6f);
    const float sr0 = __builtin_amdgcn_rcpf(1.f + __expf(-(float)r2[0]));
    const float sr1 = __builtin_amdgcn_rcpf(1.f + __expf(-(float)r2[1]));
    bf16x2 o;
    o[0] = (__bf16)(sr0 * wkv0);
    o[1] = (__bf16)(sr1 * wkv1);
    *(bf16x2*)(rb + idx) = o;
  }
}

// ---------------- launch -------------------------------------------------------
extern "C" void kernel_launch(void* const* d_in, const int* in_sizes, int n_in,
                              void* d_out, int out_size, void* d_ws, size_t ws_size,
                              hipStream_t stream) {
  const float* x  = (const float*)d_in[0];
  const float* Wk = (const float*)d_in[1];
  const float* Wv = (const float*)d_in[2];
  const float* Wr = (const float*)d_in[3];
  const float* Wo = (const float*)d_in[4];
  const float* td = (const float*)d_in[5];
  const float* tf = (const float*)d_in[6];
  float* out = (float*)d_out;

  char* ws = (char*)d_ws;
  const size_t matX = (size_t)MDIM * KDIM * sizeof(__bf16);  // 33.5 MB
  const size_t matW = (size_t)NDIM * KDIM * sizeof(__bf16);  // 8.4 MB
  __bf16* xb  = (__bf16*)(ws);
  __bf16* wkb = (__bf16*)(ws + matX);
  __bf16* wvb = (__bf16*)(ws + matX + matW);
  __bf16* wrb = (__bf16*)(ws + matX + 2 * matW);
  __bf16* wob = (__bf16*)(ws + matX + 3 * matW);
  __bf16* kb  = (__bf16*)(ws + matX + 4 * matW);
  __bf16* vb  = (__bf16*)(ws + 2 * matX + 4 * matW);
  __bf16* rb  = (__bf16*)(ws + 3 * matX + 4 * matW);
  float* nsum = (float*)(ws + 4 * matX + 4 * matW);
  float* dsum = nsum + (size_t)NCHUNK * BB * CDIM;
  // ws use: 4*33.5MB + 4*8.4MB + 4MB ~= 172 MB

  dim3 blk(256);
  cvt_x<<<dim3(MDIM * KDIM / (8 * 256)), blk, 0, stream>>>(x, xb);
  cvt_w<<<dim3(NDIM * KDIM / (8 * 256), 4), blk, 0, stream>>>(
      Wk, Wv, Wr, Wo, wkb, wvb, wrb, wob);

  dim3 gq(MDIM / 128, NDIM / 128, 3);
  gemm_qkv<<<gq, blk, 0, stream>>>(xb, wkb, wvb, wrb, kb, vb, rb);
  dim3 gw(CDIM / 512, NCHUNK, BB);
  wkv_summary<<<gw, blk, 0, stream>>>(kb, vb, td, tf, nsum, dsum);
  wkv_apply<<<gw, blk, 0, stream>>>(kb, vb, rb, td, tf, nsum, dsum);
  dim3 go(MDIM / 128, NDIM / 128, 1);
  gemm_o<<<go, blk, 0, stream>>>(rb, wob, out);
}

// Round 6
// 526.753 us; speedup vs baseline: 1.3358x; 1.0037x over previous
//
#include <hip/hip_runtime.h>
#include <hip/hip_bf16.h>

using bf16 = __hip_bfloat16;
using floatx4 = __attribute__((ext_vector_type(4))) float;
using bf16x8  = __attribute__((ext_vector_type(8))) __bf16;
using bf16x2  = __attribute__((ext_vector_type(2))) __bf16;

#define MDIM 8192   // B*T
#define NDIM 2048   // C
#define KDIM 2048   // C
#define TSEQ 2048   // T
#define BB   4      // batch
#define CDIM 2048   // C
#define NCHUNK 64
#define TCHUNK 32   // TSEQ/NCHUNK

typedef __attribute__((address_space(1))) void gvoid_t;
typedef __attribute__((address_space(3))) void lvoid_t;

__device__ __forceinline__ void load_lds16(const void* g, void* l) {
  __builtin_amdgcn_global_load_lds((gvoid_t*)(void*)g, (lvoid_t*)l, 16, 0, 0);
}

// ---------------- fp32 -> bf16 convert: all 5 matrices, one launch ------------
// slice 0..3 = quarters of x (same size as one weight matrix); 4..7 = Wk,Wv,Wr,Wo
__global__ __launch_bounds__(256) void cvt_all(
    const float* __restrict__ x,
    const float* __restrict__ Wk, const float* __restrict__ Wv,
    const float* __restrict__ Wr, const float* __restrict__ Wo,
    __bf16* __restrict__ xb,
    __bf16* __restrict__ wkb, __bf16* __restrict__ wvb,
    __bf16* __restrict__ wrb, __bf16* __restrict__ wob) {
  const size_t WN = (size_t)NDIM * KDIM;
  const int slice = blockIdx.y;
  const float* s;
  __bf16* d;
  if (slice < 4) { s = x + (size_t)slice * WN; d = xb + (size_t)slice * WN; }
  else {
    s = (slice == 4) ? Wk : (slice == 5) ? Wv : (slice == 6) ? Wr : Wo;
    d = (slice == 4) ? wkb : (slice == 5) ? wvb : (slice == 6) ? wrb : wob;
  }
  const int i = (blockIdx.x * 256 + threadIdx.x) * 8;
  float4 a = *(const float4*)(s + i);
  float4 b = *(const float4*)(s + i + 4);
  bf16x8 o;
  o[0] = (__bf16)a.x; o[1] = (__bf16)a.y; o[2] = (__bf16)a.z; o[3] = (__bf16)a.w;
  o[4] = (__bf16)b.x; o[5] = (__bf16)b.y; o[6] = (__bf16)b.z; o[7] = (__bf16)b.w;
  *(bf16x8*)(d + i) = o;
}

// ---------------- GEMM: C[m,n] = sum_k A[m,k] * B[n,k], bf16 in, fp32 acc -----
// 128x128 tile, BK=32, 256 threads = 4 waves in 2x2, each wave 4x4 MFMA 16x16x32.
// LDS XOR-swizzle (R5, verified conflict-free + coalesced):
//   chunk (row r, half h) at index r*4 + (h ^ ((r>>1)&3)).
// __launch_bounds__(256,4): force <=64 VGPR so 4 blocks/CU fit (64V+64A=128/wave).
template <typename CT>
__device__ __forceinline__ void gemm_body(const __bf16* __restrict__ A,
                                          const __bf16* __restrict__ B,
                                          CT* __restrict__ C) {
  __shared__ __bf16 sA[128 * 32];
  __shared__ __bf16 sB[128 * 32];
  const int tid  = threadIdx.x;
  const int lane = tid & 63;
  const int wave = tid >> 6;
  const int wm = (wave >> 1) * 64;
  const int wn = (wave & 1) * 64;
  const int bm = blockIdx.x, bn = blockIdx.y;

  floatx4 acc[4][4] = {};

  // staging source (swizzled within 64B line)
  const int srow  = tid >> 2;                       // 0..63
  const int shalf = (tid & 3) ^ ((tid >> 3) & 3);   // within-line permute
  const __bf16* Ag = A + (size_t)(bm * 128 + srow) * KDIM + shalf * 8;
  const __bf16* Bg = B + (size_t)(bn * 128 + srow) * KDIM + shalf * 8;
  __bf16* sAp = sA + tid * 8;   // dest chunk tid
  __bf16* sBp = sB + tid * 8;

  // frag-read chunk indices (K-loop-invariant)
  const int fr  = lane & 15;
  const int fk4 = lane >> 4;
  int chA[4], chB[4];
#pragma unroll
  for (int i = 0; i < 4; ++i) {
    const int ra = wm + i * 16 + fr;
    const int rb = wn + i * 16 + fr;
    chA[i] = (ra << 2) | (fk4 ^ ((ra >> 1) & 3));
    chB[i] = (rb << 2) | (fk4 ^ ((rb >> 1) & 3));
  }

  for (int kt = 0; kt < KDIM; kt += 32) {
    load_lds16(Ag,                      sAp);
    load_lds16(Ag + (size_t)64 * KDIM,  sAp + 2048);  // chunks 256..511 = rows 64..127
    load_lds16(Bg,                      sBp);
    load_lds16(Bg + (size_t)64 * KDIM,  sBp + 2048);
    Ag += 32; Bg += 32;
    __syncthreads();

    bf16x8 af[4], bfr[4];
#pragma unroll
    for (int i = 0; i < 4; ++i)
      af[i] = *(const bf16x8*)(sA + chA[i] * 8);
#pragma unroll
    for (int j = 0; j < 4; ++j)
      bfr[j] = *(const bf16x8*)(sB + chB[j] * 8);
#pragma unroll
    for (int i = 0; i < 4; ++i)
#pragma unroll
      for (int j = 0; j < 4; ++j)
        acc[i][j] = __builtin_amdgcn_mfma_f32_16x16x32_bf16(af[i], bfr[j], acc[i][j], 0, 0, 0);
    __syncthreads();
  }

  // C/D layout: col = lane&15, row = (lane>>4)*4 + reg
  const int crow = (lane >> 4) * 4;
  const int ccol = lane & 15;
#pragma unroll
  for (int i = 0; i < 4; ++i)
#pragma unroll
    for (int j = 0; j < 4; ++j) {
      const size_t r0 = (size_t)(bm * 128 + wm + i * 16 + crow);
      const int    c0 = bn * 128 + wn + j * 16 + ccol;
#pragma unroll
      for (int rg = 0; rg < 4; ++rg)
        C[(r0 + rg) * NDIM + c0] = (CT)(acc[i][j][rg]);
    }
}

__global__ __launch_bounds__(256, 4) void gemm_qkv(const __bf16* __restrict__ x,
                                                   const __bf16* __restrict__ Wk,
                                                   const __bf16* __restrict__ Wv,
                                                   const __bf16* __restrict__ Wr,
                                                   __bf16* __restrict__ kb,
                                                   __bf16* __restrict__ vb,
                                                   __bf16* __restrict__ rb) {
  const __bf16* Bsel = (blockIdx.z == 0) ? Wk : (blockIdx.z == 1) ? Wv : Wr;
  __bf16*       Csel = (blockIdx.z == 0) ? kb : (blockIdx.z == 1) ? vb : rb;
  gemm_body<__bf16>(x, Bsel, Csel);
}

__global__ __launch_bounds__(256, 4) void gemm_o(const __bf16* __restrict__ A,
                                                 const __bf16* __restrict__ B,
                                                 float* __restrict__ C) {
  gemm_body<float>(A, B, C);
}

// ---------------- WKV blocked scan (3-phase), 2 channels/thread ----------------
// Phase 1: per (b, chunk, c) chunk summary (num,den) from zero state.
__global__ __launch_bounds__(256) void wkv_summary(
    const __bf16* __restrict__ kb, const __bf16* __restrict__ vb,
    const float* __restrict__ td, const float* __restrict__ tf,
    float* __restrict__ nsum, float* __restrict__ dsum) {
  const int c0 = (blockIdx.x * 256 + threadIdx.x) * 2;
  const int chunk = blockIdx.y;
  const int b = blockIdx.z;
  const float dc0 = __expf(-__expf(td[c0]));
  const float dc1 = __expf(-__expf(td[c0 + 1]));
  const float fi0 = __expf(tf[c0]);
  const float fi1 = __expf(tf[c0 + 1]);
  size_t base = ((size_t)b * TSEQ + (size_t)chunk * TCHUNK) * CDIM + c0;
  float n0 = 0.f, d0 = 0.f, n1 = 0.f, d1 = 0.f;
#pragma unroll 4
  for (int t = 0; t < TCHUNK; ++t) {
    bf16x2 k2 = *(const bf16x2*)(kb + base + (size_t)t * CDIM);
    bf16x2 v2 = *(const bf16x2*)(vb + base + (size_t)t * CDIM);
    float k0f = fminf(fmaxf((float)k2[0], -10.f), 10.f);
    float k1f = fminf(fmaxf((float)k2[1], -10.f), 10.f);
    float w0 = __expf(k0f), w1 = __expf(k1f);
    if (chunk == 0 && t == 0) { w0 *= fi0; w1 *= fi1; }
    n0 = dc0 * n0 + w0 * (float)v2[0];
    d0 = dc0 * d0 + w0;
    n1 = dc1 * n1 + w1 * (float)v2[1];
    d1 = dc1 * d1 + w1;
  }
  const size_t si = (size_t)(chunk * BB + b) * CDIM + c0;
  *(float2*)(nsum + si) = make_float2(n0, n1);
  *(float2*)(dsum + si) = make_float2(d0, d1);
}

// Phase 2: in-place exclusive scan over chunks: slot j <- state BEFORE chunk j.
__global__ __launch_bounds__(256) void wkv_scan(
    const float* __restrict__ td,
    float* __restrict__ nsum, float* __restrict__ dsum) {
  const int c0 = (blockIdx.x * 256 + threadIdx.x) * 2;
  const int b = blockIdx.y;
  const float dT0 = __expf(-__expf(td[c0]) * (float)TCHUNK);
  const float dT1 = __expf(-__expf(td[c0 + 1]) * (float)TCHUNK);
  float pn0 = 0.f, pd0 = 0.f, pn1 = 0.f, pd1 = 0.f;
  for (int j = 0; j < NCHUNK; ++j) {
    const size_t si = (size_t)(j * BB + b) * CDIM + c0;
    float2 Sn = *(const float2*)(nsum + si);
    float2 Sd = *(const float2*)(dsum + si);
    *(float2*)(nsum + si) = make_float2(pn0, pn1);
    *(float2*)(dsum + si) = make_float2(pd0, pd1);
    pn0 = dT0 * pn0 + Sn.x;  pn1 = dT1 * pn1 + Sn.y;
    pd0 = dT0 * pd0 + Sd.x;  pd1 = dT1 * pd1 + Sd.y;
  }
}

// Phase 3: load prefix, replay chunk, fuse sigmoid(r)*wkv in-place over rb.
__global__ __launch_bounds__(256) void wkv_apply(
    const __bf16* __restrict__ kb, const __bf16* __restrict__ vb,
    __bf16* __restrict__ rb,
    const float* __restrict__ td, const float* __restrict__ tf,
    const float* __restrict__ nsum, const float* __restrict__ dsum) {
  const int c0 = (blockIdx.x * 256 + threadIdx.x) * 2;
  const int chunk = blockIdx.y;
  const int b = blockIdx.z;
  const float dc0 = __expf(-__expf(td[c0]));
  const float dc1 = __expf(-__expf(td[c0 + 1]));
  const float fi0 = __expf(tf[c0]);
  const float fi1 = __expf(tf[c0 + 1]);

  const size_t si = (size_t)(chunk * BB + b) * CDIM + c0;
  float2 pn = *(const float2*)(nsum + si);
  float2 pd = *(const float2*)(dsum + si);
  float n0 = pn.x, n1 = pn.y, d0 = pd.x, d1 = pd.y;

  size_t base = ((size_t)b * TSEQ + (size_t)chunk * TCHUNK) * CDIM + c0;
#pragma unroll 2
  for (int t = 0; t < TCHUNK; ++t) {
    const size_t idx = base + (size_t)t * CDIM;
    bf16x2 k2 = *(const bf16x2*)(kb + idx);
    bf16x2 v2 = *(const bf16x2*)(vb + idx);
    bf16x2 r2 = *(const bf16x2*)(rb + idx);
    float k0f = fminf(fmaxf((float)k2[0], -10.f), 10.f);
    float k1f = fminf(fmaxf((float)k2[1], -10.f), 10.f);
    float w0 = __expf(k0f), w1 = __expf(k1f);
    if (chunk == 0 && t == 0) { w0 *= fi0; w1 *= fi1; }
    n0 = dc0 * n0 + w0 * (float)v2[0];
    d0 = dc0 * d0 + w0;
    n1 = dc1 * n1 + w1 * (float)v2[1];
    d1 = dc1 * d1 + w1;
    const float wkv0 = n0 * __builtin_amdgcn_rcpf(d0 + 1e-6f);
    const float wkv1 = n1 * __builtin_amdgcn_rcpf(d1 + 1e-6f);
    const float sr0 = __builtin_amdgcn_rcpf(1.f + __expf(-(float)r2[0]));
    const float sr1 = __builtin_amdgcn_rcpf(1.f + __expf(-(float)r2[1]));
    bf16x2 o;
    o[0] = (__bf16)(sr0 * wkv0);
    o[1] = (__bf16)(sr1 * wkv1);
    *(bf16x2*)(rb + idx) = o;
  }
}

// ---------------- launch -------------------------------------------------------
extern "C" void kernel_launch(void* const* d_in, const int* in_sizes, int n_in,
                              void* d_out, int out_size, void* d_ws, size_t ws_size,
                              hipStream_t stream) {
  const float* x  = (const float*)d_in[0];
  const float* Wk = (const float*)d_in[1];
  const float* Wv = (const float*)d_in[2];
  const float* Wr = (const float*)d_in[3];
  const float* Wo = (const float*)d_in[4];
  const float* td = (const float*)d_in[5];
  const float* tf = (const float*)d_in[6];
  float* out = (float*)d_out;

  char* ws = (char*)d_ws;
  const size_t matX = (size_t)MDIM * KDIM * sizeof(__bf16);  // 33.5 MB
  const size_t matW = (size_t)NDIM * KDIM * sizeof(__bf16);  // 8.4 MB
  __bf16* xb  = (__bf16*)(ws);
  __bf16* wkb = (__bf16*)(ws + matX);
  __bf16* wvb = (__bf16*)(ws + matX + matW);
  __bf16* wrb = (__bf16*)(ws + matX + 2 * matW);
  __bf16* wob = (__bf16*)(ws + matX + 3 * matW);
  __bf16* kb  = (__bf16*)(ws + matX + 4 * matW);
  __bf16* vb  = (__bf16*)(ws + 2 * matX + 4 * matW);
  __bf16* rb  = (__bf16*)(ws + 3 * matX + 4 * matW);
  float* nsum = (float*)(ws + 4 * matX + 4 * matW);
  float* dsum = nsum + (size_t)NCHUNK * BB * CDIM;
  // ws use: 4*33.5MB + 4*8.4MB + 4MB ~= 172 MB

  dim3 blk(256);
  cvt_all<<<dim3(NDIM * KDIM / (8 * 256), 8), blk, 0, stream>>>(
      x, Wk, Wv, Wr, Wo, xb, wkb, wvb, wrb, wob);

  dim3 gq(MDIM / 128, NDIM / 128, 3);
  gemm_qkv<<<gq, blk, 0, stream>>>(xb, wkb, wvb, wrb, kb, vb, rb);
  dim3 gw(CDIM / 512, NCHUNK, BB);
  wkv_summary<<<gw, blk, 0, stream>>>(kb, vb, td, tf, nsum, dsum);
  wkv_scan<<<dim3(CDIM / 512, BB), blk, 0, stream>>>(td, nsum, dsum);
  wkv_apply<<<gw, blk, 0, stream>>>(kb, vb, rb, td, tf, nsum, dsum);
  dim3 go(MDIM / 128, NDIM / 128, 1);
  gemm_o<<<go, blk, 0, stream>>>(rb, wob, out);
}